// Round 3
// baseline (684.394 us; speedup 1.0000x reference)
//
#include <hip/hip_runtime.h>
#include <math.h>

// Problem constants
#define B_   128
#define I_   2048
#define DIN  8
#define J_   16
#define D_   16
#define JD   256          // J_*D_ = threads per block
#define IT   16           // i's per workgroup
#define NIT  (I_/IT)      // 128 i-tiles
#define BPG  8            // b's per workgroup
#define NBG  (B_/BPG)     // 16
#define CP   20           // padded il-stride for logit/c LDS rows (16B-aligned)

// 16-lane (DPP row) sum — pure VALU, no LDS pipe. After the 4 rotations every
// lane in the 16-lane row holds the full sum.
template <int CTRL>
__device__ __forceinline__ float dpp_add(float v) {
    int t = __builtin_amdgcn_update_dpp(0, __float_as_int(v), CTRL, 0xF, 0xF, true);
    return v + __int_as_float(t);
}
__device__ __forceinline__ float row_sum16(float v) {
    v = dpp_add<0x128>(v);   // row_ror:8
    v = dpp_add<0x124>(v);   // row_ror:4
    v = dpp_add<0x122>(v);   // row_ror:2
    v = dpp_add<0x121>(v);   // row_ror:1
    return v;
}

// ---------------------------------------------------------------------------
// Pass kernel (streaming W, DPP reductions).
// thread t <-> (j = t>>4, d = t&15). Logit layout in LDS: [bb][j][il] rows of
// CP=20 floats. Phase A keeps logit(il==d) in a register (cndmask select) and
// writes LDS once per bb. Softmax: one thread per (bb,il) row, serial over j.
// Phase C re-streams W, reads c as 16-lane broadcasts.
// ---------------------------------------------------------------------------
template <int PASS>
__global__ __launch_bounds__(256, 8) void caps_pass(
    const float* __restrict__ x,        // [B, I, DIN]
    const float* __restrict__ W,        // [J, I, D, DIN]
    const float* __restrict__ vsum,     // [B, J, D]  (PASS==1 only)
    float* __restrict__ s_partial)      // [NIT, B, JD]
{
    const int it = blockIdx.x;
    const int bg = blockIdx.y;
    const int i0 = it * IT;
    const int b0 = bg * BPG;
    const int t  = threadIdx.x;         // 0..255
    const int j  = t >> 4;              // 0..15
    const int d  = t & 15;              // 0..15

    __shared__ float x_lds[BPG][IT][DIN];                 // 4 KB
    __shared__ float bl_lds[PASS ? BPG * J_ * CP : 1];    // 10 KB (PASS=1)

    // Stage x tile: 8 b x 16 i x 8 f = 1024 floats = 1 float4/thread.
    {
        const int bb = t >> 5, il = (t >> 1) & 15, h = t & 1;
        const float4* src = reinterpret_cast<const float4*>(
            x + ((size_t)(b0 + bb) * I_ + (i0 + il)) * DIN) + h;
        float4 a = *src;
        reinterpret_cast<float4*>(&x_lds[bb][il][0])[h] = a;
    }

    const float* wbase = W + (((size_t)j * I_ + i0) * D_ + d) * DIN;

    float s_acc[BPG];
    #pragma unroll
    for (int bb = 0; bb < BPG; ++bb) s_acc[bb] = 0.f;

    if (PASS == 1) {
        float vs[BPG];
        #pragma unroll
        for (int bb = 0; bb < BPG; ++bb)
            vs[bb] = vsum[(size_t)(b0 + bb) * JD + t];

        float psel[BPG];
        #pragma unroll
        for (int bb = 0; bb < BPG; ++bb) psel[bb] = 0.f;

        __syncthreads();

        // ---- Phase A: logits, kept in registers until one write per bb ----
        #pragma unroll 2
        for (int il = 0; il < IT; ++il) {
            const float4* wp = reinterpret_cast<const float4*>(
                wbase + (size_t)il * (D_ * DIN));
            float4 w0 = wp[0], w1 = wp[1];
            #pragma unroll
            for (int bb = 0; bb < BPG; ++bb) {
                const float4* xv =
                    reinterpret_cast<const float4*>(&x_lds[bb][il][0]);
                float4 xa = xv[0], xb = xv[1];
                float u = w0.x * xa.x + w0.y * xa.y + w0.z * xa.z +
                          w0.w * xa.w + w1.x * xb.x + w1.y * xb.y +
                          w1.z * xb.z + w1.w * xb.w;
                float p = row_sum16(vs[bb] * u);   // all 16 lanes get the sum
                psel[bb] = (d == il) ? p : psel[bb];
            }
        }
        // lane (j,d) holds logit[bb][j][il=d]
        #pragma unroll
        for (int bb = 0; bb < BPG; ++bb)
            bl_lds[(bb * J_ + j) * CP + d] = psel[bb];
        __syncthreads();

        // ---- Softmax over j: one thread per (bb,il) row ----
        if (t < BPG * IT) {
            const int bb = t >> 4, il = t & 15;
            float* base = &bl_lds[(bb * J_) * CP + il];
            float l[J_];
            #pragma unroll
            for (int k = 0; k < J_; ++k) l[k] = base[k * CP];
            float mx = l[0];
            #pragma unroll
            for (int k = 1; k < J_; ++k) mx = fmaxf(mx, l[k]);
            float sum = 0.f;
            #pragma unroll
            for (int k = 0; k < J_; ++k) {
                l[k] = __expf(l[k] - mx);
                sum += l[k];
            }
            const float inv = 1.0f / sum;
            #pragma unroll
            for (int k = 0; k < J_; ++k) base[k * CP] = l[k] * inv;
        }
        __syncthreads();

        // ---- Phase C: weighted accumulate (c reads are 16-lane broadcasts) --
        #pragma unroll 2
        for (int il = 0; il < IT; ++il) {
            const float4* wp = reinterpret_cast<const float4*>(
                wbase + (size_t)il * (D_ * DIN));
            float4 w0 = wp[0], w1 = wp[1];
            #pragma unroll
            for (int bb = 0; bb < BPG; ++bb) {
                const float4* xv =
                    reinterpret_cast<const float4*>(&x_lds[bb][il][0]);
                float4 xa = xv[0], xb = xv[1];
                float u = w0.x * xa.x + w0.y * xa.y + w0.z * xa.z +
                          w0.w * xa.w + w1.x * xb.x + w1.y * xb.y +
                          w1.z * xb.z + w1.w * xb.w;
                const float c = bl_lds[(bb * J_ + j) * CP + il];
                s_acc[bb] += c * u;
            }
        }
    } else {
        __syncthreads();
        // ---- PASS 0: uniform c = 1/16, single W stream ----
        #pragma unroll 2
        for (int il = 0; il < IT; ++il) {
            const float4* wp = reinterpret_cast<const float4*>(
                wbase + (size_t)il * (D_ * DIN));
            float4 w0 = wp[0], w1 = wp[1];
            #pragma unroll
            for (int bb = 0; bb < BPG; ++bb) {
                const float4* xv =
                    reinterpret_cast<const float4*>(&x_lds[bb][il][0]);
                float4 xa = xv[0], xb = xv[1];
                float u = w0.x * xa.x + w0.y * xa.y + w0.z * xa.z +
                          w0.w * xa.w + w1.x * xb.x + w1.y * xb.y +
                          w1.z * xb.z + w1.w * xb.w;
                s_acc[bb] += u;
            }
        }
        #pragma unroll
        for (int bb = 0; bb < BPG; ++bb) s_acc[bb] *= (1.0f / 16.0f);
    }

    #pragma unroll
    for (int bb = 0; bb < BPG; ++bb)
        s_partial[((size_t)it * B_ + (b0 + bb)) * JD + t] = s_acc[bb];
}

// ---------------------------------------------------------------------------
// Reduce over i-tiles + squash (DPP d-reduce).
// MODE 0: vout = squash(s)        (v0)
// MODE 1: vout = vA + squash(s)   (v0 + v1, logits-linearity trick)
// MODE 2: vout = squash(s)        (final output)
// ---------------------------------------------------------------------------
template <int MODE>
__global__ __launch_bounds__(256) void caps_reduce(
    const float* __restrict__ s_partial,  // [NIT, B, JD]
    const float* __restrict__ vA,         // [B, JD] (MODE==1 only)
    float* __restrict__ vout)             // [B, JD]
{
    const int b = blockIdx.x;
    const int t = threadIdx.x;

    float acc = 0.f;
    #pragma unroll 8
    for (int it = 0; it < NIT; ++it)
        acc += s_partial[((size_t)it * B_ + b) * JD + t];

    const float sq = row_sum16(acc * acc);
    const float scale = sq / (1.0f + sq) * rsqrtf(sq + 1e-7f);
    float v = scale * acc;
    if (MODE == 1) v += vA[(size_t)b * JD + t];
    vout[(size_t)b * JD + t] = v;
}

extern "C" void kernel_launch(void* const* d_in, const int* in_sizes, int n_in,
                              void* d_out, int out_size, void* d_ws,
                              size_t ws_size, hipStream_t stream) {
    const float* x = (const float*)d_in[0];   // [128, 2048, 8]
    const float* W = (const float*)d_in[1];   // [16, 2048, 16, 8]
    float* out = (float*)d_out;               // [128, 16, 16]

    // Workspace (floats): s_partial[NIT*B*JD] | vA[B*JD] | vB[B*JD]
    float* s_partial = (float*)d_ws;
    float* vA = s_partial + (size_t)NIT * B_ * JD;
    float* vB = vA + (size_t)B_ * JD;

    dim3 grid(NIT, NBG), blk(256);

    // r=0: uniform c -> s0 -> v0
    caps_pass<0><<<grid, blk, 0, stream>>>(x, W, nullptr, s_partial);
    caps_reduce<0><<<B_, 256, 0, stream>>>(s_partial, nullptr, vA);
    // r=1: logits = v0·u_hat -> s1 -> vB = v0 + v1
    caps_pass<1><<<grid, blk, 0, stream>>>(x, W, vA, s_partial);
    caps_reduce<1><<<B_, 256, 0, stream>>>(s_partial, vA, vB);
    // r=2: logits = (v0+v1)·u_hat -> s2 -> output v2
    caps_pass<1><<<grid, blk, 0, stream>>>(x, W, vB, s_partial);
    caps_reduce<2><<<B_, 256, 0, stream>>>(s_partial, nullptr, out);
}

// Round 4
// 207.406 us; speedup vs baseline: 3.2998x; 3.2998x over previous
//
#include <hip/hip_runtime.h>
#include <math.h>

// Problem constants
#define B_   128
#define I_   2048
#define DIN  8
#define J_   16
#define D_   16
#define JD   256          // J_*D_ = threads per block
#define IT   16           // i's per workgroup
#define NIT  (I_/IT)      // 128 i-tiles
#define BPG  8            // b's per workgroup
#define NBG  (B_/BPG)     // 16
#define CP   20           // padded il-stride for logit/c LDS rows

// 16-lane (DPP row) sum — pure VALU, no LDS pipe. After the 4 rotations every
// lane in the 16-lane row holds the full sum.
template <int CTRL>
__device__ __forceinline__ float dpp_add(float v) {
    int t = __builtin_amdgcn_update_dpp(0, __float_as_int(v), CTRL, 0xF, 0xF, true);
    return v + __int_as_float(t);
}
__device__ __forceinline__ float row_sum16(float v) {
    v = dpp_add<0x128>(v);   // row_ror:8
    v = dpp_add<0x124>(v);   // row_ror:4
    v = dpp_add<0x122>(v);   // row_ror:2
    v = dpp_add<0x121>(v);   // row_ror:1
    return v;
}

// ---------------------------------------------------------------------------
// Pass kernel (streaming W, DPP reductions).
// thread t <-> (j = t>>4, d = t&15). Logit layout in LDS: [bb][j][il] rows of
// CP=20 floats. Phase A keeps logit(il==d) in a register (cndmask select) and
// writes LDS once per bb. Softmax: one thread per (bb,il) row, serial over j.
// Phase C re-streams W, reads c as 16-lane broadcasts.
// NOTE: __launch_bounds__(256, 4) — (256, 8) forces a 64-VGPR cap that the
// compiler answers with catastrophic scratch spills (round-3 regression:
// FETCH 550 MB, 305 us). Natural allocation is ~50 VGPR, which still allows
// 8 waves/SIMD.
// ---------------------------------------------------------------------------
template <int PASS>
__global__ __launch_bounds__(256, 4) void caps_pass(
    const float* __restrict__ x,        // [B, I, DIN]
    const float* __restrict__ W,        // [J, I, D, DIN]
    const float* __restrict__ vsum,     // [B, J, D]  (PASS==1 only)
    float* __restrict__ s_partial)      // [NIT, B, JD]
{
    const int it = blockIdx.x;
    const int bg = blockIdx.y;
    const int i0 = it * IT;
    const int b0 = bg * BPG;
    const int t  = threadIdx.x;         // 0..255
    const int j  = t >> 4;              // 0..15
    const int d  = t & 15;              // 0..15

    __shared__ float x_lds[BPG][IT][DIN];                 // 4 KB
    __shared__ float bl_lds[PASS ? BPG * J_ * CP : 1];    // 10 KB (PASS=1)

    // Stage x tile: 8 b x 16 i x 8 f = 1024 floats = 1 float4/thread.
    {
        const int bb = t >> 5, il = (t >> 1) & 15, h = t & 1;
        const float4* src = reinterpret_cast<const float4*>(
            x + ((size_t)(b0 + bb) * I_ + (i0 + il)) * DIN) + h;
        float4 a = *src;
        reinterpret_cast<float4*>(&x_lds[bb][il][0])[h] = a;
    }

    const float* wbase = W + (((size_t)j * I_ + i0) * D_ + d) * DIN;

    float s_acc[BPG];
    #pragma unroll
    for (int bb = 0; bb < BPG; ++bb) s_acc[bb] = 0.f;

    if (PASS == 1) {
        float vs[BPG];
        #pragma unroll
        for (int bb = 0; bb < BPG; ++bb)
            vs[bb] = vsum[(size_t)(b0 + bb) * JD + t];

        float psel[BPG];
        #pragma unroll
        for (int bb = 0; bb < BPG; ++bb) psel[bb] = 0.f;

        __syncthreads();

        // ---- Phase A: logits, kept in registers until one write per bb ----
        #pragma unroll 2
        for (int il = 0; il < IT; ++il) {
            const float4* wp = reinterpret_cast<const float4*>(
                wbase + (size_t)il * (D_ * DIN));
            float4 w0 = wp[0], w1 = wp[1];
            #pragma unroll
            for (int bb = 0; bb < BPG; ++bb) {
                const float4* xv =
                    reinterpret_cast<const float4*>(&x_lds[bb][il][0]);
                float4 xa = xv[0], xb = xv[1];
                float u = w0.x * xa.x + w0.y * xa.y + w0.z * xa.z +
                          w0.w * xa.w + w1.x * xb.x + w1.y * xb.y +
                          w1.z * xb.z + w1.w * xb.w;
                float p = row_sum16(vs[bb] * u);   // all 16 lanes get the sum
                psel[bb] = (d == il) ? p : psel[bb];
            }
        }
        // lane (j,d) holds logit[bb][j][il=d]
        #pragma unroll
        for (int bb = 0; bb < BPG; ++bb)
            bl_lds[(bb * J_ + j) * CP + d] = psel[bb];
        __syncthreads();

        // ---- Softmax over j: one thread per (bb,il) row ----
        if (t < BPG * IT) {
            const int bb = t >> 4, il = t & 15;
            float* base = &bl_lds[(bb * J_) * CP + il];
            float l[J_];
            #pragma unroll
            for (int k = 0; k < J_; ++k) l[k] = base[k * CP];
            float mx = l[0];
            #pragma unroll
            for (int k = 1; k < J_; ++k) mx = fmaxf(mx, l[k]);
            float sum = 0.f;
            #pragma unroll
            for (int k = 0; k < J_; ++k) {
                l[k] = __expf(l[k] - mx);
                sum += l[k];
            }
            const float inv = 1.0f / sum;
            #pragma unroll
            for (int k = 0; k < J_; ++k) base[k * CP] = l[k] * inv;
        }
        __syncthreads();

        // ---- Phase C: weighted accumulate (c reads are 16-lane broadcasts) --
        #pragma unroll 2
        for (int il = 0; il < IT; ++il) {
            const float4* wp = reinterpret_cast<const float4*>(
                wbase + (size_t)il * (D_ * DIN));
            float4 w0 = wp[0], w1 = wp[1];
            #pragma unroll
            for (int bb = 0; bb < BPG; ++bb) {
                const float4* xv =
                    reinterpret_cast<const float4*>(&x_lds[bb][il][0]);
                float4 xa = xv[0], xb = xv[1];
                float u = w0.x * xa.x + w0.y * xa.y + w0.z * xa.z +
                          w0.w * xa.w + w1.x * xb.x + w1.y * xb.y +
                          w1.z * xb.z + w1.w * xb.w;
                const float c = bl_lds[(bb * J_ + j) * CP + il];
                s_acc[bb] += c * u;
            }
        }
    } else {
        __syncthreads();
        // ---- PASS 0: uniform c = 1/16, single W stream ----
        #pragma unroll 2
        for (int il = 0; il < IT; ++il) {
            const float4* wp = reinterpret_cast<const float4*>(
                wbase + (size_t)il * (D_ * DIN));
            float4 w0 = wp[0], w1 = wp[1];
            #pragma unroll
            for (int bb = 0; bb < BPG; ++bb) {
                const float4* xv =
                    reinterpret_cast<const float4*>(&x_lds[bb][il][0]);
                float4 xa = xv[0], xb = xv[1];
                float u = w0.x * xa.x + w0.y * xa.y + w0.z * xa.z +
                          w0.w * xa.w + w1.x * xb.x + w1.y * xb.y +
                          w1.z * xb.z + w1.w * xb.w;
                s_acc[bb] += u;
            }
        }
        #pragma unroll
        for (int bb = 0; bb < BPG; ++bb) s_acc[bb] *= (1.0f / 16.0f);
    }

    #pragma unroll
    for (int bb = 0; bb < BPG; ++bb)
        s_partial[((size_t)it * B_ + (b0 + bb)) * JD + t] = s_acc[bb];
}

// ---------------------------------------------------------------------------
// Reduce over i-tiles + squash (DPP d-reduce).
// MODE 0: vout = squash(s)        (v0)
// MODE 1: vout = vA + squash(s)   (v0 + v1, logits-linearity trick)
// MODE 2: vout = squash(s)        (final output)
// ---------------------------------------------------------------------------
template <int MODE>
__global__ __launch_bounds__(256) void caps_reduce(
    const float* __restrict__ s_partial,  // [NIT, B, JD]
    const float* __restrict__ vA,         // [B, JD] (MODE==1 only)
    float* __restrict__ vout)             // [B, JD]
{
    const int b = blockIdx.x;
    const int t = threadIdx.x;

    float acc = 0.f;
    #pragma unroll 8
    for (int it = 0; it < NIT; ++it)
        acc += s_partial[((size_t)it * B_ + b) * JD + t];

    const float sq = row_sum16(acc * acc);
    const float scale = sq / (1.0f + sq) * rsqrtf(sq + 1e-7f);
    float v = scale * acc;
    if (MODE == 1) v += vA[(size_t)b * JD + t];
    vout[(size_t)b * JD + t] = v;
}

extern "C" void kernel_launch(void* const* d_in, const int* in_sizes, int n_in,
                              void* d_out, int out_size, void* d_ws,
                              size_t ws_size, hipStream_t stream) {
    const float* x = (const float*)d_in[0];   // [128, 2048, 8]
    const float* W = (const float*)d_in[1];   // [16, 2048, 16, 8]
    float* out = (float*)d_out;               // [128, 16, 16]

    // Workspace (floats): s_partial[NIT*B*JD] | vA[B*JD] | vB[B*JD]
    float* s_partial = (float*)d_ws;
    float* vA = s_partial + (size_t)NIT * B_ * JD;
    float* vB = vA + (size_t)B_ * JD;

    dim3 grid(NIT, NBG), blk(256);

    // r=0: uniform c -> s0 -> v0
    caps_pass<0><<<grid, blk, 0, stream>>>(x, W, nullptr, s_partial);
    caps_reduce<0><<<B_, 256, 0, stream>>>(s_partial, nullptr, vA);
    // r=1: logits = v0·u_hat -> s1 -> vB = v0 + v1
    caps_pass<1><<<grid, blk, 0, stream>>>(x, W, vA, s_partial);
    caps_reduce<1><<<B_, 256, 0, stream>>>(s_partial, vA, vB);
    // r=2: logits = (v0+v1)·u_hat -> s2 -> output v2
    caps_pass<1><<<grid, blk, 0, stream>>>(x, W, vB, s_partial);
    caps_reduce<2><<<B_, 256, 0, stream>>>(s_partial, nullptr, out);
}

// Round 5
// 80.276 us; speedup vs baseline: 8.5255x; 2.5837x over previous
//
#include <hip/hip_runtime.h>
#include <math.h>

// Problem constants
#define B_   128
#define I_   2048
#define F_   8
#define J_   16
#define D_   16
#define JD   256
#define IT   16            // i per block
#define NIT  (I_/IT)       // 128
#define BT   16            // b per block
#define NBT  (B_/BT)       // 8
#define SROW 257           // padded slds row stride (dwords)

typedef _Float16 f16;
typedef _Float16 f16x8 __attribute__((ext_vector_type(8)));
typedef _Float16 f16x4 __attribute__((ext_vector_type(4)));
typedef float    f32x4 __attribute__((ext_vector_type(4)));

#if defined(__has_builtin)
#  if __has_builtin(__builtin_amdgcn_permlane32_swap)
#    define HAVE_PLS32 1
#  endif
#endif

// 16-lane DPP sum (reduce kernel only)
template <int CTRL>
__device__ __forceinline__ float dpp_add(float v) {
    int t = __builtin_amdgcn_update_dpp(0, __float_as_int(v), CTRL, 0xF, 0xF, true);
    return v + __int_as_float(t);
}
__device__ __forceinline__ float row_sum16(float v) {
    v = dpp_add<0x128>(v);
    v = dpp_add<0x124>(v);
    v = dpp_add<0x122>(v);
    v = dpp_add<0x121>(v);
    return v;
}

// quarter-sum for MFMA C-layout: add lane^16 (ds_swizzle) then lane^32.
__device__ __forceinline__ float fold16(float p) {
    return p + __int_as_float(__builtin_amdgcn_ds_swizzle(__float_as_int(p), 0x401F));
}
__device__ __forceinline__ float fold32(float p) {
#ifdef HAVE_PLS32
    auto r = __builtin_amdgcn_permlane32_swap(__float_as_int(p), __float_as_int(p),
                                              false, false);
    return __int_as_float(r[0]) + __int_as_float(r[1]);
#else
    return p + __shfl_xor(p, 32);
#endif
}

// ---------------------------------------------------------------------------
// f32 -> f16 conversion of W (4,194,304) then x (2,097,152). 4 elems/thread.
// ---------------------------------------------------------------------------
__global__ __launch_bounds__(256) void cvt_f16(const float* __restrict__ W,
                                               const float* __restrict__ x,
                                               f16* __restrict__ Wt,
                                               f16* __restrict__ xt) {
    const size_t NW = (size_t)J_ * I_ * D_ * F_;
    const size_t NX = (size_t)B_ * I_ * F_;
    size_t k = ((size_t)blockIdx.x * 256 + threadIdx.x) * 4;
    if (k < NW) {
        float4 a = *reinterpret_cast<const float4*>(W + k);
        f16x4 h = {(f16)a.x, (f16)a.y, (f16)a.z, (f16)a.w};
        *reinterpret_cast<f16x4*>(Wt + k) = h;
    } else {
        size_t k2 = k - NW;
        if (k2 < NX) {
            float4 a = *reinterpret_cast<const float4*>(x + k2);
            f16x4 h = {(f16)a.x, (f16)a.y, (f16)a.z, (f16)a.w};
            *reinterpret_cast<f16x4*>(xt + k2) = h;
        }
    }
}

// ---------------------------------------------------------------------------
// Pass kernel (MFMA). Block = (i-tile 16) x (b-tile 16), 4 waves <-> 4 j each.
// Lane: lb = l&15, lq = l>>4.
// Phase A (PASS=1): per (j,il): u[d,b] = mfma(W~[d,f], x~[f,b]) (K=8 of 32);
//   logit = sum_d v*u via 4 FMA + fold16 + fold32; lanes<16 write L[j][il][b].
// Softmax over j per (b,i) thread, c written in place.
// Phase C: s[d,b] per j over K=(i16,f8)=128: 4 MFMAs, B-frag = c * x~ built
//   in-register (v_pk_mul_f16). PASS=0: c = 1/16 folded as final scale.
// Epilogue: s -> LDS (padded rows) -> coalesced f16 global store.
// ---------------------------------------------------------------------------
template <int PASS>
__global__ __launch_bounds__(256) void caps_pass(
    const f16* __restrict__ Wt,     // [J][I][D][F]
    const f16* __restrict__ xt,     // [B][I][F]
    const float* __restrict__ vsum, // [B][JD] (PASS==1)
    f16* __restrict__ sp)           // [NIT][B][JD]
{
    const int it = blockIdx.x, bg = blockIdx.y;
    const int i0 = it * IT, b0 = bg * BT;
    const int t = threadIdx.x;
    const int w = t >> 6, l = t & 63;
    const int lb = l & 15, lq = l >> 4;

    __shared__ f16   xlds[IT][BT][F_];                 // 4 KB
    __shared__ float cl[PASS ? (J_ * IT * BT) : 1];    // 16 KB (PASS=1)
    __shared__ float slds[BT * SROW];                  // 16.4 KB

    // stage x~ tile: thread (b = t>>4, i = t&15) loads 8 f16 (16B) coalesced
    {
        const int b = t >> 4, i = t & 15;
        f16x8 v = *reinterpret_cast<const f16x8*>(
            xt + ((size_t)(b0 + b) * I_ + i0 + i) * F_);
        *reinterpret_cast<f16x8*>(&xlds[i][b][0]) = v;
    }

    // per-j W~ base pointers (row d = lb, f contiguous)
    const f16* wp[4];
    #pragma unroll
    for (int jj = 0; jj < 4; ++jj)
        wp[jj] = Wt + (((size_t)(w * 4 + jj) * I_ + i0) * D_ + lb) * F_;

    f32x4 zero = {0.f, 0.f, 0.f, 0.f};
    f32x4 sacc[4] = {zero, zero, zero, zero};

    if constexpr (PASS == 1) {
        // v fragments: vr[jj] = vsum[b0+lb][j][lq*4 .. +3]
        float4 vr[4];
        #pragma unroll
        for (int jj = 0; jj < 4; ++jj)
            vr[jj] = *reinterpret_cast<const float4*>(
                vsum + (size_t)(b0 + lb) * JD + (w * 4 + jj) * D_ + lq * 4);
        __syncthreads();

        // ---- Phase A: logits ----
        #pragma unroll 4
        for (int il = 0; il < IT; ++il) {
            f16x8 bf = {0, 0, 0, 0, 0, 0, 0, 0};
            if (l < 16) bf = *reinterpret_cast<const f16x8*>(&xlds[il][lb][0]);
            #pragma unroll
            for (int jj = 0; jj < 4; ++jj) {
                f16x8 af = *reinterpret_cast<const f16x8*>(wp[jj] + il * (D_ * F_));
                f32x4 u = __builtin_amdgcn_mfma_f32_16x16x32_f16(af, bf, zero, 0, 0, 0);
                float p = u[0] * vr[jj].x + u[1] * vr[jj].y +
                          u[2] * vr[jj].z + u[3] * vr[jj].w;
                p = fold32(fold16(p));
                if (l < 16) cl[(((w * 4 + jj) * IT) + il) * BT + lb] = p;
            }
        }
        __syncthreads();

        // ---- softmax over j: thread (i = t>>4, b = t&15) ----
        {
            const int i = t >> 4, b = t & 15;
            float e[J_];
            float mx = -1e30f;
            #pragma unroll
            for (int j = 0; j < J_; ++j) {
                e[j] = cl[(j * IT + i) * BT + b];
                mx = fmaxf(mx, e[j]);
            }
            float s = 0.f;
            #pragma unroll
            for (int j = 0; j < J_; ++j) { e[j] = __expf(e[j] - mx); s += e[j]; }
            const float inv = 1.f / s;
            #pragma unroll
            for (int j = 0; j < J_; ++j) cl[(j * IT + i) * BT + b] = e[j] * inv;
        }
        __syncthreads();
    } else {
        __syncthreads();
    }

    // ---- Phase C: s-GEMM, K = (i,f) = 128 -> 4 MFMAs per j ----
    #pragma unroll
    for (int m = 0; m < 4; ++m) {
        const int i = m * 4 + lq;
        f16x8 xf = *reinterpret_cast<const f16x8*>(&xlds[i][lb][0]);
        #pragma unroll
        for (int jj = 0; jj < 4; ++jj) {
            f16x8 bf;
            if constexpr (PASS == 1) {
                const float cf = cl[(((w * 4 + jj) * IT) + i) * BT + lb];
                const f16 ch = (f16)cf;
                bf = xf * ch;           // 4x v_pk_mul_f16
            } else {
                bf = xf;
            }
            f16x8 af = *reinterpret_cast<const f16x8*>(wp[jj] + i * (D_ * F_));
            sacc[jj] = __builtin_amdgcn_mfma_f32_16x16x32_f16(af, bf, sacc[jj], 0, 0, 0);
        }
    }

    // ---- epilogue: transpose via LDS (padded rows), coalesced f16 store ----
    #pragma unroll
    for (int jj = 0; jj < 4; ++jj) {
        if constexpr (PASS == 0) sacc[jj] *= 0.0625f;
        const int j = w * 4 + jj;
        #pragma unroll
        for (int r = 0; r < 4; ++r)
            slds[lb * SROW + j * D_ + lq * 4 + r] = sacc[jj][r];
    }
    __syncthreads();
    {
        const int b = t >> 4, seg = t & 15;
        float o[16];
        #pragma unroll
        for (int k = 0; k < 16; ++k)
            o[k] = slds[b * SROW + seg * 16 + k];
        f16x8 o0 = {(f16)o[0], (f16)o[1], (f16)o[2],  (f16)o[3],
                    (f16)o[4], (f16)o[5], (f16)o[6],  (f16)o[7]};
        f16x8 o1 = {(f16)o[8], (f16)o[9], (f16)o[10], (f16)o[11],
                    (f16)o[12], (f16)o[13], (f16)o[14], (f16)o[15]};
        f16* dst = sp + ((size_t)it * B_ + b0 + b) * JD + seg * 16;
        *reinterpret_cast<f16x8*>(dst) = o0;
        *reinterpret_cast<f16x8*>(dst + 8) = o1;
    }
}

// ---------------------------------------------------------------------------
// Reduce over i-tiles + squash. 512 threads: (jd = t&255, half h = t>>8).
// MODE 0: vA = squash(s); MODE 1: vB = vA + squash(s); MODE 2: out = squash(s)
// ---------------------------------------------------------------------------
template <int MODE>
__global__ __launch_bounds__(512) void caps_reduce(
    const f16* __restrict__ sp,    // [NIT][B][JD] f16
    const float* __restrict__ vA,  // [B][JD] (MODE==1)
    float* __restrict__ vout)      // [B][JD]
{
    const int b = blockIdx.x;
    const int t = threadIdx.x;
    const int jd = t & 255, h = t >> 8;

    float acc = 0.f;
    const f16* p = sp + ((size_t)(h * 64) * B_ + b) * JD + jd;
    #pragma unroll 16
    for (int i = 0; i < 64; ++i)
        acc += (float)p[(size_t)i * B_ * JD];

    __shared__ float red[256];
    if (h) red[jd] = acc;
    __syncthreads();
    if (!h) {
        acc += red[jd];
        const float sq = row_sum16(acc * acc);
        const float scale = sq / (1.f + sq) * rsqrtf(sq + 1e-7f);
        float v = scale * acc;
        if (MODE == 1) v += vA[(size_t)b * JD + jd];
        vout[(size_t)b * JD + jd] = v;
    }
}

extern "C" void kernel_launch(void* const* d_in, const int* in_sizes, int n_in,
                              void* d_out, int out_size, void* d_ws,
                              size_t ws_size, hipStream_t stream) {
    const float* x = (const float*)d_in[0];   // [128, 2048, 8]
    const float* W = (const float*)d_in[1];   // [16, 2048, 16, 8]
    float* out = (float*)d_out;               // [128, 16, 16]

    // Workspace: Wt f16 | xt f16 | sp f16 | vA f32 | vB f32  (~21.2 MB)
    f16* Wt = (f16*)d_ws;
    f16* xt = Wt + (size_t)J_ * I_ * D_ * F_;        // +4,194,304
    f16* sp = xt + (size_t)B_ * I_ * F_;             // +2,097,152
    float* vA = (float*)(sp + (size_t)NIT * B_ * JD);
    float* vB = vA + (size_t)B_ * JD;

    const int TOT4 = (int)(((size_t)J_ * I_ * D_ * F_ + (size_t)B_ * I_ * F_) / 4);
    cvt_f16<<<TOT4 / 256, 256, 0, stream>>>(W, x, Wt, xt);

    dim3 grid(NIT, NBT), blk(256);

    // r=0: uniform c -> s0 -> v0
    caps_pass<0><<<grid, blk, 0, stream>>>(Wt, xt, nullptr, sp);
    caps_reduce<0><<<B_, 512, 0, stream>>>(sp, nullptr, vA);
    // r=1: logits = v0.u_hat -> s1 -> vB = v0 + v1
    caps_pass<1><<<grid, blk, 0, stream>>>(Wt, xt, vA, sp);
    caps_reduce<1><<<B_, 512, 0, stream>>>(sp, vA, vB);
    // r=2: logits = (v0+v1).u_hat -> s2 -> out
    caps_pass<1><<<grid, blk, 0, stream>>>(Wt, xt, vB, sp);
    caps_reduce<2><<<B_, 512, 0, stream>>>(sp, nullptr, out);
}